// Round 2
// baseline (2235.820 us; speedup 1.0000x reference)
//
#include <hip/hip_runtime.h>

#define PAD 68

__device__ __forceinline__ float sigm_(float x) { return 1.0f / (1.0f + __expf(-x)); }
__device__ __forceinline__ float tanh_(float x) {
    x = fminf(fmaxf(x, -15.0f), 15.0f);
    const float e = __expf(2.0f * x);
    return (e - 1.0f) / (e + 1.0f);
}

__device__ __forceinline__ float dot8(float4 ha, float4 hb, const float* __restrict__ w, float acc) {
    const float4 w0 = *(const float4*)w;
    const float4 w1 = *(const float4*)(w + 4);
    acc = __builtin_fmaf(ha.x, w0.x, acc);
    acc = __builtin_fmaf(ha.y, w0.y, acc);
    acc = __builtin_fmaf(ha.z, w0.z, acc);
    acc = __builtin_fmaf(ha.w, w0.w, acc);
    acc = __builtin_fmaf(hb.x, w1.x, acc);
    acc = __builtin_fmaf(hb.y, w1.y, acc);
    acc = __builtin_fmaf(hb.z, w1.z, acc);
    acc = __builtin_fmaf(hb.w, w1.w, acc);
    return acc;
}

// One workgroup per batch row b. 256 threads = 32 node-groups x 8 lanes.
// All 3 message-passing iterations + final MLP fused; state lives in LDS.
// launch_bounds(256,2): VGPR cap 256 — R1 showed (256,4) forced VGPR=64 and
// ~5.4 GB of scratch spill traffic (WRITE_SIZE 2.1 GB vs 0.5 MB legit output).
__global__ __launch_bounds__(256, 2) void gnn_fused(
    const float* __restrict__ init_features,  // (B,32,3)
    const float* __restrict__ edge_weight,    // (B,992)
    const float* __restrict__ noise_info,     // (B,1)
    const float* __restrict__ hx_init,        // (B,32,64)
    const float* __restrict__ x_hat,          // (B,32)
    const float* __restrict__ var_in,         // (B,32)
    const float* __restrict__ W1a, const float* __restrict__ b1a,
    const float* __restrict__ W2a, const float* __restrict__ b2a,
    const float* __restrict__ W2b, const float* __restrict__ b2b,
    const float* __restrict__ W2c, const float* __restrict__ b2c,
    const float* __restrict__ W3a, const float* __restrict__ b3a,
    const float* __restrict__ W3b, const float* __restrict__ b3b,
    const float* __restrict__ W3c, const float* __restrict__ b3c,
    const float* __restrict__ Wih, const float* __restrict__ Whh,
    const float* __restrict__ bih, const float* __restrict__ bhh,
    const float* __restrict__ W4,  const float* __restrict__ b4,
    float* __restrict__ out)                  // (B,32,4)
{
    const int b = blockIdx.x;
    const int t = threadIdx.x;
    const int a = t >> 3;   // node index this thread serves (0..31)
    const int s = t & 7;    // sub-lane within node group (0..7)

    __shared__ float s_edge[992];
    __shared__ float s_A1[32][PAD];   // nodes[u]@W2a[0:8] + b2a + nw*W2a[17]  (pad 68: bank spread)
    __shared__ float s_B1[32][PAD];   // nodes[u]@W2a[8:16]
    __shared__ float s_hx[32][PAD];   // GRU hidden state
    __shared__ float s_nodes[32][8];  // node features / gru_read

    // --- stage constant-per-b data ---
    for (int i = t; i < 992; i += 256) s_edge[i] = edge_weight[(size_t)b*992 + i];
    const float nw = noise_info[b];
    for (int i = t; i < 2048; i += 256) s_hx[i >> 6][i & 63] = hx_init[(size_t)b*2048 + i];

    // --- iteration-0 nodes: x_init(5) @ W1a(5,8) + b1a ---
    {
        const float* f = init_features + ((size_t)b*32 + a)*3;
        float xi[5];
        xi[0] = f[0]; xi[1] = f[1]; xi[2] = f[2];
        xi[3] = x_hat[(size_t)b*32 + a];
        xi[4] = var_in[(size_t)b*32 + a];
        float acc = b1a[s];
        #pragma unroll
        for (int k = 0; k < 5; ++k) acc = __builtin_fmaf(xi[k], W1a[k*8+s], acc);
        s_nodes[a][s] = acc;
    }
    __syncthreads();

    for (int it = 0; it < 3; ++it) {
        // --- A1/B1 precompute: folds layer-1 node + noise contributions ---
        {
            float nd[8];
            #pragma unroll
            for (int k = 0; k < 8; ++k) nd[k] = s_nodes[a][k];
            #pragma unroll
            for (int hh = 0; hh < 8; ++hh) {
                const int h = s*8 + hh;
                float accA = __builtin_fmaf(nw, W2a[1088 + h], b2a[h]);
                float accB = 0.0f;
                #pragma unroll
                for (int k = 0; k < 8; ++k) {
                    accA = __builtin_fmaf(nd[k], W2a[k*64 + h], accA);
                    accB = __builtin_fmaf(nd[k], W2a[(8+k)*64 + h], accB);
                }
                s_A1[a][h] = accA;
                s_B1[a][h] = accB;
            }
        }
        __syncthreads();

        // --- edge MLP: 8 lanes per node a, each lane does edges j = r*8+s ---
        float accout[8];
        #pragma unroll
        for (int c = 0; c < 8; ++c) accout[c] = 0.0f;

        for (int r = 0; r < 4; ++r) {
            const int j = r*8 + s;
            if (j < 31) {
                const int tb = (j < a) ? j : (j + 1);
                const float ew = s_edge[a*31 + j];
                float m2[32];
                #pragma unroll
                for (int n = 0; n < 32; ++n) m2[n] = b2b[n];
                for (int kb = 0; kb < 4; ++kb) {           // stream layer1 -> layer2 in k-blocks of 16
                    float m1[16];
                    #pragma unroll
                    for (int q = 0; q < 4; ++q) {
                        const int h = kb*16 + q*4;
                        const float4 A4 = *(const float4*)&s_A1[a][h];
                        const float4 B4 = *(const float4*)&s_B1[tb][h];
                        m1[q*4+0] = fmaxf(__builtin_fmaf(ew, W2a[1024+h  ], A4.x + B4.x), 0.f);
                        m1[q*4+1] = fmaxf(__builtin_fmaf(ew, W2a[1024+h+1], A4.y + B4.y), 0.f);
                        m1[q*4+2] = fmaxf(__builtin_fmaf(ew, W2a[1024+h+2], A4.z + B4.z), 0.f);
                        m1[q*4+3] = fmaxf(__builtin_fmaf(ew, W2a[1024+h+3], A4.w + B4.w), 0.f);
                    }
                    #pragma unroll
                    for (int kk = 0; kk < 16; ++kk) {      // weights uniform -> SGPR, v_fmac v,s,v
                        const int h = kb*16 + kk;
                        #pragma unroll
                        for (int n = 0; n < 32; ++n)
                            m2[n] = __builtin_fmaf(m1[kk], W2b[h*32+n], m2[n]);
                    }
                }
                #pragma unroll
                for (int c = 0; c < 8; ++c) {
                    float acc = b2c[c];
                    #pragma unroll
                    for (int n = 0; n < 32; ++n)
                        acc = __builtin_fmaf(fmaxf(m2[n], 0.f), W2c[n*8+c], acc);
                    accout[c] += fmaxf(acc, 0.f);
                }
            }
        }
        // reduce the 8 lanes of each node group; afterwards EVERY lane holds
        // the full per-node sum for all 8 channels (no LDS round-trip needed)
        #pragma unroll
        for (int mask = 1; mask < 8; mask <<= 1) {
            #pragma unroll
            for (int c = 0; c < 8; ++c)
                accout[c] += __shfl_xor(accout[c], mask, 64);
        }

        // --- GRU: thread handles channels c = s*8..s*8+7 of row (b,a) ---
        float accR[8], accZ[8], giN[8], ghN[8];
        #pragma unroll
        for (int cc = 0; cc < 8; ++cc) {
            const int c = s*8 + cc;
            float r0 = bih[c]      + bhh[c];
            float z0 = bih[64+c]   + bhh[64+c];
            float n0 = bih[128+c];
            #pragma unroll
            for (int k = 0; k < 8; ++k) {
                r0 = __builtin_fmaf(accout[k], Wih[c*8+k],       r0);
                z0 = __builtin_fmaf(accout[k], Wih[(64+c)*8+k],  z0);
                n0 = __builtin_fmaf(accout[k], Wih[(128+c)*8+k], n0);
            }
            accR[cc] = r0; accZ[cc] = z0; giN[cc] = n0;
            ghN[cc] = bhh[128+c];
        }
        #pragma unroll
        for (int kb = 0; kb < 8; ++kb) {
            const float4 ha = *(const float4*)&s_hx[a][kb*8];
            const float4 hb = *(const float4*)&s_hx[a][kb*8+4];
            #pragma unroll
            for (int cc = 0; cc < 8; ++cc) {
                const int c = s*8 + cc;
                accR[cc] = dot8(ha, hb, &Whh[(size_t)c*64      + kb*8], accR[cc]);
                accZ[cc] = dot8(ha, hb, &Whh[(size_t)(64+c)*64 + kb*8], accZ[cc]);
                ghN[cc]  = dot8(ha, hb, &Whh[(size_t)(128+c)*64+ kb*8], ghN[cc]);
            }
        }
        float hnew[8];
        #pragma unroll
        for (int cc = 0; cc < 8; ++cc) {
            const float rr = sigm_(accR[cc]);
            const float zz = sigm_(accZ[cc]);
            const float nn = tanh_(giN[cc] + rr*ghN[cc]);
            hnew[cc] = (1.0f - zz)*nn + zz*s_hx[a][s*8+cc];
        }
        __syncthreads();   // all s_hx reads done before overwrite
        #pragma unroll
        for (int cc = 0; cc < 8; ++cc) s_hx[a][s*8+cc] = hnew[cc];
        __syncthreads();

        // --- gru_read / next nodes: hx(64) @ W4(64,8) + b4 ---
        {
            float acc = b4[s];
            #pragma unroll
            for (int k = 0; k < 64; ++k)
                acc = __builtin_fmaf(s_hx[a][k], W4[k*8+s], acc);
            s_nodes[a][s] = acc;
        }
        __syncthreads();
    }

    // --- final MLP (no activations): 8 -> 64 -> 32 -> 4 ---
    {
        float nd[8];
        #pragma unroll
        for (int k = 0; k < 8; ++k) nd[k] = s_nodes[a][k];
        #pragma unroll
        for (int hh = 0; hh < 8; ++hh) {
            const int h = s*8 + hh;
            float acc = b3a[h];
            #pragma unroll
            for (int k = 0; k < 8; ++k) acc = __builtin_fmaf(nd[k], W3a[k*64+h], acc);
            s_A1[a][h] = acc;      // reuse s_A1 as v1 scratch
        }
    }
    __syncthreads();
    {
        float acc[4];
        #pragma unroll
        for (int i = 0; i < 4; ++i) acc[i] = b3b[s*4+i];
        #pragma unroll
        for (int k = 0; k < 64; ++k) {
            const float v = s_A1[a][k];
            #pragma unroll
            for (int i = 0; i < 4; ++i)
                acc[i] = __builtin_fmaf(v, W3b[k*32 + s*4 + i], acc[i]);
        }
        #pragma unroll
        for (int i = 0; i < 4; ++i) s_B1[a][s*4+i] = acc[i];   // reuse s_B1 as v2 scratch
    }
    __syncthreads();
    if (s < 4) {
        float acc = b3c[s];
        #pragma unroll
        for (int n = 0; n < 32; ++n)
            acc = __builtin_fmaf(s_B1[a][n], W3c[n*4+s], acc);
        out[((size_t)b*32 + a)*4 + s] = acc;
    }
}

extern "C" void kernel_launch(void* const* d_in, const int* in_sizes, int n_in,
                              void* d_out, int out_size, void* d_ws, size_t ws_size,
                              hipStream_t stream)
{
    const float* init_features = (const float*)d_in[0];
    const float* edge_weight   = (const float*)d_in[1];
    const float* noise_info    = (const float*)d_in[2];
    const float* hx_init       = (const float*)d_in[3];
    /* d_in[4] = cons — unused by the reference forward */
    const float* x_hat = (const float*)d_in[5];
    const float* var_i = (const float*)d_in[6];
    const float* W1a = (const float*)d_in[7];  const float* b1a = (const float*)d_in[8];
    const float* W2a = (const float*)d_in[9];  const float* b2a = (const float*)d_in[10];
    const float* W2b = (const float*)d_in[11]; const float* b2b = (const float*)d_in[12];
    const float* W2c = (const float*)d_in[13]; const float* b2c = (const float*)d_in[14];
    const float* W3a = (const float*)d_in[15]; const float* b3a = (const float*)d_in[16];
    const float* W3b = (const float*)d_in[17]; const float* b3b = (const float*)d_in[18];
    const float* W3c = (const float*)d_in[19]; const float* b3c = (const float*)d_in[20];
    const float* Wih = (const float*)d_in[21]; const float* Whh = (const float*)d_in[22];
    const float* bih = (const float*)d_in[23]; const float* bhh = (const float*)d_in[24];
    const float* W4  = (const float*)d_in[25]; const float* b4  = (const float*)d_in[26];

    gnn_fused<<<dim3(1024), dim3(256), 0, stream>>>(
        init_features, edge_weight, noise_info, hx_init, x_hat, var_i,
        W1a, b1a, W2a, b2a, W2b, b2b, W2c, b2c,
        W3a, b3a, W3b, b3b, W3c, b3c,
        Wih, Whh, bih, bhh, W4, b4, (float*)d_out);
}

// Round 3
// 403.355 us; speedup vs baseline: 5.5431x; 5.5431x over previous
//
#include <hip/hip_runtime.h>

#define PADH 68   // row pitch (floats) for 64-col LDS tiles

__device__ __forceinline__ float sigm_(float x) { return 1.0f / (1.0f + __expf(-x)); }
__device__ __forceinline__ float tanh_(float x) {
    x = fminf(fmaxf(x, -15.0f), 15.0f);
    const float e = __expf(2.0f * x);
    return (e - 1.0f) / (e + 1.0f);
}

// 2 batch rows per block; 256 threads = 4 waves; wave = 2 rows x 32 nodes.
// ALL weight reads are wave-uniform (w from readfirstlane + loop vars) ->
// scalar s_load through K$; zero per-lane weight VMEM (R2's spill source).
__global__ __launch_bounds__(256, 2) void gnn_fused(
    const float* __restrict__ init_features,  // (B,32,3)
    const float* __restrict__ edge_weight,    // (B,992)
    const float* __restrict__ noise_info,     // (B,1)
    const float* __restrict__ hx_init,        // (B,32,64)
    const float* __restrict__ x_hat,          // (B,32)
    const float* __restrict__ var_in,         // (B,32)
    const float* __restrict__ W1a, const float* __restrict__ b1a,
    const float* __restrict__ W2a, const float* __restrict__ b2a,
    const float* __restrict__ W2b, const float* __restrict__ b2b,
    const float* __restrict__ W2c, const float* __restrict__ b2c,
    const float* __restrict__ W3a, const float* __restrict__ b3a,
    const float* __restrict__ W3b, const float* __restrict__ b3b,
    const float* __restrict__ W3c, const float* __restrict__ b3c,
    const float* __restrict__ Wih, const float* __restrict__ Whh,
    const float* __restrict__ bih, const float* __restrict__ bhh,
    const float* __restrict__ W4,  const float* __restrict__ b4,
    float* __restrict__ out)                  // (B,32,4)
{
    const int t  = threadIdx.x;
    const int w  = __builtin_amdgcn_readfirstlane(t >> 6); // wave id 0..3, SGPR-uniform
    const int l  = t & 63;    // node slot = bl*32 + a
    const int bl = l >> 5;    // local batch row (0/1)
    const int a  = l & 31;    // node index
    const int b0 = blockIdx.x * 2;
    const int bg = b0 + bl;   // global batch row for this lane

    __shared__ float s_edge[1984];        // [2][992]
    __shared__ float s_A1[64][PADH];      // nodes@W2a[0:8]+b2a+nw*W2a[17]; later v1 scratch
    __shared__ float s_B1[64][PADH];      // nodes@W2a[8:16];               later v2 scratch
    __shared__ float s_hx[64][PADH];      // GRU hidden state
    __shared__ float s_nodes[64][8];      // node features / gru_read
    __shared__ float s_part[4][64][9];    // per-wave edge-sum partials (pad 9: 2-way banks)

    // ---- stage per-block data (coalesced) ----
    for (int i = t; i < 1984; i += 256) s_edge[i] = edge_weight[(size_t)b0*992 + i];
    for (int i = t; i < 4096; i += 256) s_hx[i >> 6][i & 63] = hx_init[(size_t)b0*2048 + i];
    const float nw = noise_info[bg];

    // ---- iteration-0 nodes: x_init(5) @ W1a(5,8) + b1a; wave w does channels w*2, w*2+1 ----
    {
        const float* f = init_features + ((size_t)bg*32 + a)*3;
        const float xi0 = f[0], xi1 = f[1], xi2 = f[2];
        const float xi3 = x_hat[(size_t)bg*32 + a];
        const float xi4 = var_in[(size_t)bg*32 + a];
        #pragma unroll
        for (int cc = 0; cc < 2; ++cc) {
            const int c = w*2 + cc;                       // uniform
            float acc = b1a[c];
            acc = __builtin_fmaf(xi0, W1a[0*8+c], acc);
            acc = __builtin_fmaf(xi1, W1a[1*8+c], acc);
            acc = __builtin_fmaf(xi2, W1a[2*8+c], acc);
            acc = __builtin_fmaf(xi3, W1a[3*8+c], acc);
            acc = __builtin_fmaf(xi4, W1a[4*8+c], acc);
            s_nodes[l][c] = acc;
        }
    }
    __syncthreads();

    #pragma unroll 1
    for (int it = 0; it < 3; ++it) {
        // ---- A: fold layer-1: A1 = nodes@W2a[0:8]+b2a+nw*W2a[17], B1 = nodes@W2a[8:16].
        //      wave w covers h = w*16 .. w*16+15 (uniform weight indices). ----
        {
            float nd[8];
            *(float4*)&nd[0] = *(const float4*)&s_nodes[l][0];
            *(float4*)&nd[4] = *(const float4*)&s_nodes[l][4];
            #pragma unroll
            for (int hh = 0; hh < 16; ++hh) {
                const int h = w*16 + hh;
                float accA = __builtin_fmaf(nw, W2a[1088 + h], b2a[h]);
                float accB = 0.0f;
                #pragma unroll
                for (int k = 0; k < 8; ++k) {
                    accA = __builtin_fmaf(nd[k], W2a[k*64 + h],     accA);
                    accB = __builtin_fmaf(nd[k], W2a[(8+k)*64 + h], accB);
                }
                s_A1[l][h] = accA;
                s_B1[l][h] = accB;
            }
        }
        __syncthreads();

        // ---- B: edge MLP. Wave w handles edges j = w + 4i of every node. ----
        float accout[8];
        #pragma unroll
        for (int c = 0; c < 8; ++c) accout[c] = 0.0f;

        #pragma unroll 1
        for (int i = 0; i < 8; ++i) {
            const int j = w + 4*i;            // uniform; wave 3 skips j==31
            if (j < 31) {
                const int tbv = (j < a) ? j : (j + 1);
                const float ew = s_edge[bl*992 + a*31 + j];
                float m2[32];
                #pragma unroll
                for (int n = 0; n < 32; ++n) m2[n] = b2b[n];
                #pragma unroll 1
                for (int kb = 0; kb < 4; ++kb) {          // stream L1 -> L2 in k-blocks of 16
                    float m1[16];
                    #pragma unroll
                    for (int q = 0; q < 4; ++q) {
                        const int h = kb*16 + q*4;
                        const float4 A4 = *(const float4*)&s_A1[l][h];
                        const float4 B4 = *(const float4*)&s_B1[bl*32 + tbv][h];
                        m1[q*4+0] = fmaxf(__builtin_fmaf(ew, W2a[1024+h+0], A4.x + B4.x), 0.f);
                        m1[q*4+1] = fmaxf(__builtin_fmaf(ew, W2a[1024+h+1], A4.y + B4.y), 0.f);
                        m1[q*4+2] = fmaxf(__builtin_fmaf(ew, W2a[1024+h+2], A4.z + B4.z), 0.f);
                        m1[q*4+3] = fmaxf(__builtin_fmaf(ew, W2a[1024+h+3], A4.w + B4.w), 0.f);
                    }
                    #pragma unroll
                    for (int kk = 0; kk < 16; ++kk) {      // W2b idx uniform -> s_load
                        #pragma unroll
                        for (int n = 0; n < 32; ++n)
                            m2[n] = __builtin_fmaf(m1[kk], W2b[(kb*16+kk)*32 + n], m2[n]);
                    }
                }
                #pragma unroll
                for (int n = 0; n < 32; ++n) m2[n] = fmaxf(m2[n], 0.f);
                #pragma unroll
                for (int c = 0; c < 8; ++c) {
                    float acc = b2c[c];
                    #pragma unroll
                    for (int n = 0; n < 32; ++n)
                        acc = __builtin_fmaf(m2[n], W2c[n*8 + c], acc);
                    accout[c] += fmaxf(acc, 0.f);
                }
            }
        }
        #pragma unroll
        for (int c = 0; c < 8; ++c) s_part[w][l][c] = accout[c];
        __syncthreads();

        // ---- C: GRU. Lane owns node (bl,a); wave w owns channels c = w*16..+15. ----
        float h[64];                          // static-indexed only (rule #20)
        #pragma unroll
        for (int q = 0; q < 16; ++q)
            *(float4*)&h[q*4] = *(const float4*)&s_hx[l][q*4];
        float x8[8];
        #pragma unroll
        for (int k = 0; k < 8; ++k)
            x8[k] = s_part[0][l][k] + s_part[1][l][k] + s_part[2][l][k] + s_part[3][l][k];
        __syncthreads();                      // every lane captured h_old before any write

        #pragma unroll 1
        for (int cc = 0; cc < 16; ++cc) {
            const int c = w*16 + cc;          // uniform -> Wih/Whh/bias all s_load
            float r0 = bih[c]      + bhh[c];
            float z0 = bih[64+c]   + bhh[64+c];
            float n0 = bih[128+c];
            float nh = bhh[128+c];
            #pragma unroll
            for (int k = 0; k < 8; ++k) {
                r0 = __builtin_fmaf(x8[k], Wih[c*8+k],        r0);
                z0 = __builtin_fmaf(x8[k], Wih[(64+c)*8+k],   z0);
                n0 = __builtin_fmaf(x8[k], Wih[(128+c)*8+k],  n0);
            }
            #pragma unroll
            for (int k = 0; k < 64; ++k) {
                r0 = __builtin_fmaf(h[k], Whh[c*64+k],        r0);
                z0 = __builtin_fmaf(h[k], Whh[(64+c)*64+k],   z0);
                nh = __builtin_fmaf(h[k], Whh[(128+c)*64+k],  nh);
            }
            const float rr = sigm_(r0);
            const float zz = sigm_(z0);
            const float nn = tanh_(n0 + rr*nh);
            const float hold = s_hx[l][c];    // still old: only this thread writes (l,c)
            s_hx[l][c] = (1.0f - zz)*nn + zz*hold;
        }
        __syncthreads();

        // ---- D: gru_read = hx_new @ W4 + b4; wave w does channels w*2, w*2+1 ----
        {
            const int c0 = w*2, c1 = w*2 + 1;
            float acc0 = b4[c0], acc1 = b4[c1];
            #pragma unroll
            for (int q = 0; q < 16; ++q) {
                const float4 hv = *(const float4*)&s_hx[l][q*4];
                acc0 = __builtin_fmaf(hv.x, W4[(q*4+0)*8 + c0], acc0);
                acc0 = __builtin_fmaf(hv.y, W4[(q*4+1)*8 + c0], acc0);
                acc0 = __builtin_fmaf(hv.z, W4[(q*4+2)*8 + c0], acc0);
                acc0 = __builtin_fmaf(hv.w, W4[(q*4+3)*8 + c0], acc0);
                acc1 = __builtin_fmaf(hv.x, W4[(q*4+0)*8 + c1], acc1);
                acc1 = __builtin_fmaf(hv.y, W4[(q*4+1)*8 + c1], acc1);
                acc1 = __builtin_fmaf(hv.z, W4[(q*4+2)*8 + c1], acc1);
                acc1 = __builtin_fmaf(hv.w, W4[(q*4+3)*8 + c1], acc1);
            }
            s_nodes[l][c0] = acc0;
            s_nodes[l][c1] = acc1;
        }
        __syncthreads();
    }

    // ---- final MLP: 8 -> 64 -> 32 -> 4 (no activations) ----
    {   // v1 = nodes@W3a + b3a; wave w covers h = w*16..+15; store in s_A1
        float nd[8];
        *(float4*)&nd[0] = *(const float4*)&s_nodes[l][0];
        *(float4*)&nd[4] = *(const float4*)&s_nodes[l][4];
        #pragma unroll
        for (int hh = 0; hh < 16; ++hh) {
            const int hO = w*16 + hh;
            float acc = b3a[hO];
            #pragma unroll
            for (int k = 0; k < 8; ++k) acc = __builtin_fmaf(nd[k], W3a[k*64 + hO], acc);
            s_A1[l][hO] = acc;
        }
    }
    __syncthreads();
    {   // v2 = v1@W3b + b3b; wave w covers outputs n = w*8..+7; store in s_B1
        float acc[8];
        #pragma unroll
        for (int jj = 0; jj < 8; ++jj) acc[jj] = b3b[w*8 + jj];
        #pragma unroll
        for (int q = 0; q < 16; ++q) {
            const float4 v = *(const float4*)&s_A1[l][q*4];
            #pragma unroll
            for (int jj = 0; jj < 8; ++jj) {
                const int n = w*8 + jj;
                acc[jj] = __builtin_fmaf(v.x, W3b[(q*4+0)*32 + n], acc[jj]);
                acc[jj] = __builtin_fmaf(v.y, W3b[(q*4+1)*32 + n], acc[jj]);
                acc[jj] = __builtin_fmaf(v.z, W3b[(q*4+2)*32 + n], acc[jj]);
                acc[jj] = __builtin_fmaf(v.w, W3b[(q*4+3)*32 + n], acc[jj]);
            }
        }
        #pragma unroll
        for (int jj = 0; jj < 8; ++jj) s_B1[l][w*8 + jj] = acc[jj];
    }
    __syncthreads();
    {   // z = v2@W3c + b3c; wave w writes output channel w (NC=4)
        float acc = b3c[w];
        #pragma unroll
        for (int n = 0; n < 32; ++n)
            acc = __builtin_fmaf(s_B1[l][n], W3c[n*4 + w], acc);
        out[((size_t)bg*32 + a)*4 + w] = acc;
    }
}

extern "C" void kernel_launch(void* const* d_in, const int* in_sizes, int n_in,
                              void* d_out, int out_size, void* d_ws, size_t ws_size,
                              hipStream_t stream)
{
    const float* init_features = (const float*)d_in[0];
    const float* edge_weight   = (const float*)d_in[1];
    const float* noise_info    = (const float*)d_in[2];
    const float* hx_init       = (const float*)d_in[3];
    /* d_in[4] = cons — unused by the reference forward */
    const float* x_hat = (const float*)d_in[5];
    const float* var_i = (const float*)d_in[6];
    const float* W1a = (const float*)d_in[7];  const float* b1a = (const float*)d_in[8];
    const float* W2a = (const float*)d_in[9];  const float* b2a = (const float*)d_in[10];
    const float* W2b = (const float*)d_in[11]; const float* b2b = (const float*)d_in[12];
    const float* W2c = (const float*)d_in[13]; const float* b2c = (const float*)d_in[14];
    const float* W3a = (const float*)d_in[15]; const float* b3a = (const float*)d_in[16];
    const float* W3b = (const float*)d_in[17]; const float* b3b = (const float*)d_in[18];
    const float* W3c = (const float*)d_in[19]; const float* b3c = (const float*)d_in[20];
    const float* Wih = (const float*)d_in[21]; const float* Whh = (const float*)d_in[22];
    const float* bih = (const float*)d_in[23]; const float* bhh = (const float*)d_in[24];
    const float* W4  = (const float*)d_in[25]; const float* b4  = (const float*)d_in[26];

    gnn_fused<<<dim3(512), dim3(256), 0, stream>>>(
        init_features, edge_weight, noise_info, hx_init, x_hat, var_i,
        W1a, b1a, W2a, b2a, W2b, b2b, W2c, b2c,
        W3a, b3a, W3b, b3b, W3c, b3c,
        Wih, Whh, bih, bhh, W4, b4, (float*)d_out);
}